// Round 1
// baseline (65602.606 us; speedup 1.0000x reference)
//
#include <hip/hip_runtime.h>
#include <hip/hip_bf16.h>
#include <math.h>

#define T_STEPS 1024
#define HDIM    2048
#define ADIM    64
#define NBLK    256
#define NTHR    512   // 8 waves/block -> 2048 waves total = one wave per output row

// ---------------------------------------------------------------------------
// Device-scope generation barrier (all NBLK blocks co-resident via coop launch)
// ---------------------------------------------------------------------------
__device__ __forceinline__ void grid_sync(unsigned int* bar) {
    __syncthreads();
    if (threadIdx.x == 0) {
        __threadfence();  // release: flush this block's stores device-wide
        unsigned int g = __hip_atomic_load(bar + 1, __ATOMIC_RELAXED, __HIP_MEMORY_SCOPE_AGENT);
        unsigned int a = __hip_atomic_fetch_add(bar, 1u, __ATOMIC_ACQ_REL, __HIP_MEMORY_SCOPE_AGENT);
        if (a == (unsigned int)(gridDim.x - 1)) {
            __hip_atomic_store(bar, 0u, __ATOMIC_RELAXED, __HIP_MEMORY_SCOPE_AGENT);
            __hip_atomic_store(bar + 1, g + 1u, __ATOMIC_RELEASE, __HIP_MEMORY_SCOPE_AGENT);
        } else {
            while (__hip_atomic_load(bar + 1, __ATOMIC_RELAXED, __HIP_MEMORY_SCOPE_AGENT) == g) {
                __builtin_amdgcn_s_sleep(1);
            }
        }
        __threadfence();  // acquire: invalidate stale cached lines
    }
    __syncthreads();
}

__device__ __forceinline__ float elu_f(float x)      { return x > 0.f ? x : expm1f(x); }
__device__ __forceinline__ float sigmoid_f(float x)  { return 1.f / (1.f + expf(-x)); }
__device__ __forceinline__ float softplus_f(float x) { return x > 0.f ? x + log1pf(expf(-x)) : log1pf(expf(x)); }

// ---------------------------------------------------------------------------
// Persistent sequential kernel: runs all T steps of the recurrence.
// Wave w owns output row j = w for every stage.
// Stage 1: gh rows (j, H+j, 2H+j) + gi (len-64 dot, 1 elem/lane) -> gates -> s0=elu(h_new)
// Stage 2: s1 = elu(fc1_w[j]·s0 + b)
// Stage 3: s_t = elu(fc2_w[j]·s1 + b)  (stored to s_all; next step's hidden)
// ---------------------------------------------------------------------------
__global__ void __launch_bounds__(NTHR, 1) gru_seq_kernel(
    const float* __restrict__ actions, const float* __restrict__ state,
    const float* __restrict__ W_ih, const float* __restrict__ W_hh,
    const float* __restrict__ b_ih, const float* __restrict__ b_hh,
    const float* __restrict__ fc1_w, const float* __restrict__ fc1_b,
    const float* __restrict__ fc2_w, const float* __restrict__ fc2_b,
    float* __restrict__ s_all, float* __restrict__ s0buf, float* __restrict__ s1buf,
    unsigned int* bar)
{
    const int lane = threadIdx.x & 63;
    const int wave = threadIdx.x >> 6;
    const int j    = blockIdx.x * (NTHR / 64) + wave;   // 0..2047

    const float4* wr4 = (const float4*)(W_hh + (size_t)j * HDIM);
    const float4* wz4 = (const float4*)(W_hh + (size_t)(HDIM + j) * HDIM);
    const float4* wn4 = (const float4*)(W_hh + (size_t)(2 * HDIM + j) * HDIM);
    const float4* f14 = (const float4*)(fc1_w + (size_t)j * HDIM);
    const float4* f24 = (const float4*)(fc2_w + (size_t)j * HDIM);

    // per-lane W_ih entries (gi dot has length 64 == wave size)
    const float wih_r = W_ih[(size_t)j * ADIM + lane];
    const float wih_z = W_ih[(size_t)(HDIM + j) * ADIM + lane];
    const float wih_n = W_ih[(size_t)(2 * HDIM + j) * ADIM + lane];

    const float bias_r = b_ih[j] + b_hh[j];
    const float bias_z = b_ih[HDIM + j] + b_hh[HDIM + j];
    const float bihn   = b_ih[2 * HDIM + j];
    const float bhhn   = b_hh[2 * HDIM + j];
    const float fb1    = fc1_b[j];
    const float fb2    = fc2_b[j];

    for (int t = 0; t < T_STEPS; ++t) {
        const float* sp = (t == 0) ? state : (s_all + (size_t)(t - 1) * HDIM);
        const float4* sp4 = (const float4*)sp;

        // ---- stage 1: GRU cell ----
        float dr = 0.f, dz = 0.f, dnH = 0.f;
        #pragma unroll
        for (int kk = 0; kk < 8; ++kk) {
            const int idx = kk * 64 + lane;
            const float4 sv = sp4[idx];
            const float4 a = wr4[idx];
            const float4 b = wz4[idx];
            const float4 c = wn4[idx];
            dr  += sv.x * a.x + sv.y * a.y + sv.z * a.z + sv.w * a.w;
            dz  += sv.x * b.x + sv.y * b.y + sv.z * b.z + sv.w * b.w;
            dnH += sv.x * c.x + sv.y * c.y + sv.z * c.z + sv.w * c.w;
        }
        const float av = actions[t * ADIM + lane];
        dr += av * wih_r;
        dz += av * wih_z;
        float dnA = av * wih_n;

        #pragma unroll
        for (int m = 32; m > 0; m >>= 1) {
            dr  += __shfl_xor(dr, m, 64);
            dz  += __shfl_xor(dz, m, 64);
            dnH += __shfl_xor(dnH, m, 64);
            dnA += __shfl_xor(dnA, m, 64);
        }
        if (lane == 0) {
            const float r  = sigmoid_f(dr + bias_r);
            const float z  = sigmoid_f(dz + bias_z);
            const float n  = tanhf(dnA + bihn + r * (dnH + bhhn));
            const float hp = sp[j];
            const float hn = (1.f - z) * n + z * hp;
            s0buf[j] = elu_f(hn);
        }
        grid_sync(bar);

        // ---- stage 2: fc1 ----
        {
            const float4* s04 = (const float4*)s0buf;
            float d1 = 0.f;
            #pragma unroll
            for (int kk = 0; kk < 8; ++kk) {
                const int idx = kk * 64 + lane;
                const float4 sv = s04[idx];
                const float4 a = f14[idx];
                d1 += sv.x * a.x + sv.y * a.y + sv.z * a.z + sv.w * a.w;
            }
            #pragma unroll
            for (int m = 32; m > 0; m >>= 1) d1 += __shfl_xor(d1, m, 64);
            if (lane == 0) s1buf[j] = elu_f(d1 + fb1);
        }
        grid_sync(bar);

        // ---- stage 3: fc2 -> s_t ----
        {
            const float4* s14 = (const float4*)s1buf;
            float d2 = 0.f;
            #pragma unroll
            for (int kk = 0; kk < 8; ++kk) {
                const int idx = kk * 64 + lane;
                const float4 sv = s14[idx];
                const float4 a = f24[idx];
                d2 += sv.x * a.x + sv.y * a.y + sv.z * a.z + sv.w * a.w;
            }
            #pragma unroll
            for (int m = 32; m > 0; m >>= 1) d2 += __shfl_xor(d2, m, 64);
            if (lane == 0) s_all[(size_t)t * HDIM + j] = elu_f(d2 + fb2);
        }
        grid_sync(bar);
    }
}

// ---------------------------------------------------------------------------
// Head GEMM: C[t, n] over n in [0,4096): n<2048 -> mean row, else std row.
// 64x64 tiles, K-panels of 32, 4x4 microtiles, fp32.
// ---------------------------------------------------------------------------
__global__ void __launch_bounds__(256) head_gemm_kernel(
    const float* __restrict__ s_all,
    const float* __restrict__ mean_w, const float* __restrict__ mean_b,
    const float* __restrict__ std_w,  const float* __restrict__ std_b,
    float* __restrict__ out)
{
    __shared__ float As[32 * 64];
    __shared__ float Bs[32 * 64];

    const int n0 = blockIdx.x * 64;          // 0..4095
    const int t0 = blockIdx.y * 64;          // 0..1023
    const bool is_std = (n0 >= HDIM);
    const float* W    = is_std ? std_w : mean_w;
    const float* bias = is_std ? std_b : mean_b;
    const int j0 = is_std ? (n0 - HDIM) : n0;

    const int tid = threadIdx.x;
    const int tx = tid & 15;      // n-subtile
    const int ty = tid >> 4;      // t-subtile

    float acc[4][4] = {};

    for (int k0 = 0; k0 < HDIM; k0 += 32) {
        __syncthreads();
        #pragma unroll
        for (int p = 0; p < 2; ++p) {
            const int id = tid + p * 256;
            const int m  = id >> 3;
            const int kk = id & 7;
            const float4 a = *(const float4*)&s_all[(size_t)(t0 + m) * HDIM + k0 + kk * 4];
            As[(kk * 4 + 0) * 64 + m] = a.x;
            As[(kk * 4 + 1) * 64 + m] = a.y;
            As[(kk * 4 + 2) * 64 + m] = a.z;
            As[(kk * 4 + 3) * 64 + m] = a.w;
            const float4 b = *(const float4*)&W[(size_t)(j0 + m) * HDIM + k0 + kk * 4];
            Bs[(kk * 4 + 0) * 64 + m] = b.x;
            Bs[(kk * 4 + 1) * 64 + m] = b.y;
            Bs[(kk * 4 + 2) * 64 + m] = b.z;
            Bs[(kk * 4 + 3) * 64 + m] = b.w;
        }
        __syncthreads();

        #pragma unroll
        for (int k = 0; k < 32; ++k) {
            const float4 a = *(const float4*)&As[k * 64 + ty * 4];
            const float4 b = *(const float4*)&Bs[k * 64 + tx * 4];
            const float am[4] = {a.x, a.y, a.z, a.w};
            const float bn[4] = {b.x, b.y, b.z, b.w};
            #pragma unroll
            for (int i = 0; i < 4; ++i)
                #pragma unroll
                for (int jj = 0; jj < 4; ++jj)
                    acc[i][jj] += am[i] * bn[jj];
        }
    }

    const size_t off = is_std ? (size_t)T_STEPS * HDIM : 0;
    #pragma unroll
    for (int i = 0; i < 4; ++i) {
        const int tt = t0 + ty * 4 + i;
        const int jc = j0 + tx * 4;
        float4 v;
        float* vp = (float*)&v;
        #pragma unroll
        for (int jj = 0; jj < 4; ++jj) {
            float val = acc[i][jj] + bias[jc + jj];
            if (is_std) val = softplus_f(val);
            vp[jj] = val;
        }
        *(float4*)&out[off + (size_t)tt * HDIM + jc] = v;
    }
}

// ---------------------------------------------------------------------------
extern "C" void kernel_launch(void* const* d_in, const int* in_sizes, int n_in,
                              void* d_out, int out_size, void* d_ws, size_t ws_size,
                              hipStream_t stream) {
    (void)in_sizes; (void)n_in; (void)out_size; (void)ws_size;
    const float* actions = (const float*)d_in[0];
    const float* state   = (const float*)d_in[1];
    const float* W_ih    = (const float*)d_in[2];
    const float* W_hh    = (const float*)d_in[3];
    const float* b_ih    = (const float*)d_in[4];
    const float* b_hh    = (const float*)d_in[5];
    const float* fc1_w   = (const float*)d_in[6];
    const float* fc1_b   = (const float*)d_in[7];
    const float* fc2_w   = (const float*)d_in[8];
    const float* fc2_b   = (const float*)d_in[9];
    const float* mean_w  = (const float*)d_in[10];
    const float* mean_b  = (const float*)d_in[11];
    const float* std_w   = (const float*)d_in[12];
    const float* std_b   = (const float*)d_in[13];
    float* out = (float*)d_out;

    float* s_all = (float*)d_ws;                       // [T, H]
    float* s0    = s_all + (size_t)T_STEPS * HDIM;     // [H]
    float* s1    = s0 + HDIM;                          // [H]
    unsigned int* bar = (unsigned int*)(s1 + HDIM);    // counter + generation

    hipMemsetAsync(bar, 0, 2 * sizeof(unsigned int), stream);

    void* args[] = { &actions, &state, &W_ih, &W_hh, &b_ih, &b_hh,
                     &fc1_w, &fc1_b, &fc2_w, &fc2_b,
                     &s_all, &s0, &s1, &bar };
    hipLaunchCooperativeKernel((const void*)gru_seq_kernel,
                               dim3(NBLK), dim3(NTHR), args, 0, stream);

    dim3 grid(4096 / 64, T_STEPS / 64);
    head_gemm_kernel<<<grid, 256, 0, stream>>>(s_all, mean_w, mean_b, std_w, std_b, out);
}

// Round 2
// 12383.389 us; speedup vs baseline: 5.2976x; 5.2976x over previous
//
#include <hip/hip_runtime.h>
#include <hip/hip_bf16.h>
#include <math.h>

#define T_STEPS 1024
#define HDIM    2048
#define ADIM    64
#define NBLK    256
#define NTHR    512
#define WPB     (NTHR / 64)   // 8 waves/block -> 2048 waves = one per output row

__device__ __forceinline__ float elu_f(float x)      { return x > 0.f ? x : expm1f(x); }
__device__ __forceinline__ float sigmoid_f(float x)  { return 1.f / (1.f + expf(-x)); }
__device__ __forceinline__ float softplus_f(float x) { return x > 0.f ? x + log1pf(expf(-x)) : log1pf(expf(x)); }

// Device-coherent (sc0 sc1, write-through / cache-bypass) relaxed atomics.
// All cross-block communication uses ONLY these, so no buffer_wbl2/buffer_inv
// cache-maintenance fences are ever required.
__device__ __forceinline__ float cloadf(const float* p) {
    return __hip_atomic_load(p, __ATOMIC_RELAXED, __HIP_MEMORY_SCOPE_AGENT);
}
__device__ __forceinline__ void cstoref(float* p, float v) {
    __hip_atomic_store(p, v, __ATOMIC_RELAXED, __HIP_MEMORY_SCOPE_AGENT);
}
__device__ __forceinline__ unsigned cloadu(const unsigned* p) {
    return __hip_atomic_load(p, __ATOMIC_RELAXED, __HIP_MEMORY_SCOPE_AGENT);
}
__device__ __forceinline__ void cstoreu(unsigned* p, unsigned v) {
    __hip_atomic_store(p, v, __ATOMIC_RELAXED, __HIP_MEMORY_SCOPE_AGENT);
}

// Fence-free grid barrier. Caller must have drained vmcnt after its coherent
// data stores (we do it unconditionally below). flags[b] / gen are monotonic
// tickets -> no reset races across reuse.
__device__ __forceinline__ void grid_barrier(unsigned* flags, unsigned* gen, unsigned ticket) {
    asm volatile("s_waitcnt vmcnt(0)" ::: "memory");  // data stores committed to coherence point
    __syncthreads();                                   // whole block's stores drained
    if (threadIdx.x == 0) cstoreu(&flags[blockIdx.x], ticket);
    if (blockIdx.x == 0 && threadIdx.x < 64) {
        const int l = threadIdx.x;
        for (;;) {
            unsigned f0 = cloadu(&flags[l]);
            unsigned f1 = cloadu(&flags[l + 64]);
            unsigned f2 = cloadu(&flags[l + 128]);
            unsigned f3 = cloadu(&flags[l + 192]);
            bool ok = (f0 >= ticket) && (f1 >= ticket) && (f2 >= ticket) && (f3 >= ticket);
            if (__all(ok)) break;
        }
        if (l == 0) cstoreu(gen, ticket);
    }
    if (threadIdx.x == 0) {
        while (cloadu(gen) < ticket) { /* spin; load RTT self-throttles */ }
    }
    __syncthreads();
}

// ---------------------------------------------------------------------------
// Persistent sequential kernel. Wave j holds ALL its weight rows in registers
// (3x W_hh rows + fc1 row + fc2 row = 160 VGPRs). Per stage: stage the 8KB
// input vector into LDS (coherent loads, once per block), dot against
// register weights, wave-reduce, lane0 coherent-stores 1 float.
// ---------------------------------------------------------------------------
__global__ void __launch_bounds__(NTHR, 2) gru_seq_kernel(
    const float* __restrict__ actions, const float* __restrict__ state,
    const float* __restrict__ W_ih, const float* __restrict__ W_hh,
    const float* __restrict__ b_ih, const float* __restrict__ b_hh,
    const float* __restrict__ fc1_w, const float* __restrict__ fc1_b,
    const float* __restrict__ fc2_w, const float* __restrict__ fc2_b,
    float* __restrict__ s_all, float* __restrict__ s0buf, float* __restrict__ s1buf,
    unsigned* flags, unsigned* gen)
{
    __shared__ float lsv[HDIM];
    const int lane = threadIdx.x & 63;
    const int wave = threadIdx.x >> 6;
    const int j    = blockIdx.x * WPB + wave;   // 0..2047

    // --- prologue: weights -> registers (lane l, chunk i holds row[256*i+4*l .. +3]) ---
    float4 wr[8], wz[8], wn[8], f1[8], f2[8];
    {
        const float4* p0 = (const float4*)(W_hh + (size_t)j * HDIM);
        const float4* p1 = (const float4*)(W_hh + (size_t)(HDIM + j) * HDIM);
        const float4* p2 = (const float4*)(W_hh + (size_t)(2 * HDIM + j) * HDIM);
        const float4* p3 = (const float4*)(fc1_w + (size_t)j * HDIM);
        const float4* p4 = (const float4*)(fc2_w + (size_t)j * HDIM);
        #pragma unroll
        for (int i = 0; i < 8; ++i) {
            wr[i] = p0[i * 64 + lane];
            wz[i] = p1[i * 64 + lane];
            wn[i] = p2[i * 64 + lane];
            f1[i] = p3[i * 64 + lane];
            f2[i] = p4[i * 64 + lane];
        }
    }
    const float wih_r = W_ih[(size_t)j * ADIM + lane];
    const float wih_z = W_ih[(size_t)(HDIM + j) * ADIM + lane];
    const float wih_n = W_ih[(size_t)(2 * HDIM + j) * ADIM + lane];
    const float bias_r = b_ih[j] + b_hh[j];
    const float bias_z = b_ih[HDIM + j] + b_hh[HDIM + j];
    const float bihn   = b_ih[2 * HDIM + j];
    const float bhhn   = b_hh[2 * HDIM + j];
    const float fb1    = fc1_b[j];
    const float fb2    = fc2_b[j];

    const float4* ls4 = (const float4*)lsv;
    unsigned ticket = 0;

    for (int t = 0; t < T_STEPS; ++t) {
        // ================= stage 1: GRU cell =================
        {
            const float* sp = (t == 0) ? state : (s_all + (size_t)(t - 1) * HDIM);
            #pragma unroll
            for (int q = 0; q < 4; ++q)
                lsv[threadIdx.x + q * NTHR] = cloadf(sp + threadIdx.x + q * NTHR);
            __syncthreads();

            float dr = 0.f, dz = 0.f, dnH = 0.f;
            #pragma unroll
            for (int i = 0; i < 8; ++i) {
                const float4 s4 = ls4[i * 64 + lane];
                dr  += s4.x * wr[i].x + s4.y * wr[i].y + s4.z * wr[i].z + s4.w * wr[i].w;
                dz  += s4.x * wz[i].x + s4.y * wz[i].y + s4.z * wz[i].z + s4.w * wz[i].w;
                dnH += s4.x * wn[i].x + s4.y * wn[i].y + s4.z * wn[i].z + s4.w * wn[i].w;
            }
            const float av = actions[t * ADIM + lane];
            dr += av * wih_r;
            dz += av * wih_z;
            float dnA = av * wih_n;
            #pragma unroll
            for (int m = 32; m > 0; m >>= 1) {
                dr  += __shfl_xor(dr, m, 64);
                dz  += __shfl_xor(dz, m, 64);
                dnH += __shfl_xor(dnH, m, 64);
                dnA += __shfl_xor(dnA, m, 64);
            }
            if (lane == 0) {
                const float r  = sigmoid_f(dr + bias_r);
                const float z  = sigmoid_f(dz + bias_z);
                const float n  = tanhf(dnA + bihn + r * (dnH + bhhn));
                const float hp = lsv[j];
                const float hn = (1.f - z) * n + z * hp;
                cstoref(&s0buf[j], elu_f(hn));
            }
        }
        grid_barrier(flags, gen, ++ticket);

        // ================= stage 2: fc1 =================
        {
            #pragma unroll
            for (int q = 0; q < 4; ++q)
                lsv[threadIdx.x + q * NTHR] = cloadf(s0buf + threadIdx.x + q * NTHR);
            __syncthreads();
            float d1 = 0.f;
            #pragma unroll
            for (int i = 0; i < 8; ++i) {
                const float4 s4 = ls4[i * 64 + lane];
                d1 += s4.x * f1[i].x + s4.y * f1[i].y + s4.z * f1[i].z + s4.w * f1[i].w;
            }
            #pragma unroll
            for (int m = 32; m > 0; m >>= 1) d1 += __shfl_xor(d1, m, 64);
            if (lane == 0) cstoref(&s1buf[j], elu_f(d1 + fb1));
        }
        grid_barrier(flags, gen, ++ticket);

        // ================= stage 3: fc2 -> s_t =================
        {
            #pragma unroll
            for (int q = 0; q < 4; ++q)
                lsv[threadIdx.x + q * NTHR] = cloadf(s1buf + threadIdx.x + q * NTHR);
            __syncthreads();
            float d2 = 0.f;
            #pragma unroll
            for (int i = 0; i < 8; ++i) {
                const float4 s4 = ls4[i * 64 + lane];
                d2 += s4.x * f2[i].x + s4.y * f2[i].y + s4.z * f2[i].z + s4.w * f2[i].w;
            }
            #pragma unroll
            for (int m = 32; m > 0; m >>= 1) d2 += __shfl_xor(d2, m, 64);
            if (lane == 0) cstoref(&s_all[(size_t)t * HDIM + j], elu_f(d2 + fb2));
        }
        grid_barrier(flags, gen, ++ticket);
    }
}

// ---------------------------------------------------------------------------
// Head GEMM (unchanged this round): C[t, n], n<2048 -> mean, else softplus(std).
// ---------------------------------------------------------------------------
__global__ void __launch_bounds__(256) head_gemm_kernel(
    const float* __restrict__ s_all,
    const float* __restrict__ mean_w, const float* __restrict__ mean_b,
    const float* __restrict__ std_w,  const float* __restrict__ std_b,
    float* __restrict__ out)
{
    __shared__ float As[32 * 64];
    __shared__ float Bs[32 * 64];

    const int n0 = blockIdx.x * 64;
    const int t0 = blockIdx.y * 64;
    const bool is_std = (n0 >= HDIM);
    const float* W    = is_std ? std_w : mean_w;
    const float* bias = is_std ? std_b : mean_b;
    const int j0 = is_std ? (n0 - HDIM) : n0;

    const int tid = threadIdx.x;
    const int tx = tid & 15;
    const int ty = tid >> 4;

    float acc[4][4] = {};

    for (int k0 = 0; k0 < HDIM; k0 += 32) {
        __syncthreads();
        #pragma unroll
        for (int p = 0; p < 2; ++p) {
            const int id = tid + p * 256;
            const int m  = id >> 3;
            const int kk = id & 7;
            const float4 a = *(const float4*)&s_all[(size_t)(t0 + m) * HDIM + k0 + kk * 4];
            As[(kk * 4 + 0) * 64 + m] = a.x;
            As[(kk * 4 + 1) * 64 + m] = a.y;
            As[(kk * 4 + 2) * 64 + m] = a.z;
            As[(kk * 4 + 3) * 64 + m] = a.w;
            const float4 b = *(const float4*)&W[(size_t)(j0 + m) * HDIM + k0 + kk * 4];
            Bs[(kk * 4 + 0) * 64 + m] = b.x;
            Bs[(kk * 4 + 1) * 64 + m] = b.y;
            Bs[(kk * 4 + 2) * 64 + m] = b.z;
            Bs[(kk * 4 + 3) * 64 + m] = b.w;
        }
        __syncthreads();

        #pragma unroll
        for (int k = 0; k < 32; ++k) {
            const float4 a = *(const float4*)&As[k * 64 + ty * 4];
            const float4 b = *(const float4*)&Bs[k * 64 + tx * 4];
            const float am[4] = {a.x, a.y, a.z, a.w};
            const float bn[4] = {b.x, b.y, b.z, b.w};
            #pragma unroll
            for (int i = 0; i < 4; ++i)
                #pragma unroll
                for (int jj = 0; jj < 4; ++jj)
                    acc[i][jj] += am[i] * bn[jj];
        }
    }

    const size_t off = is_std ? (size_t)T_STEPS * HDIM : 0;
    #pragma unroll
    for (int i = 0; i < 4; ++i) {
        const int tt = t0 + ty * 4 + i;
        const int jc = j0 + tx * 4;
        float4 v;
        float* vp = (float*)&v;
        #pragma unroll
        for (int jj = 0; jj < 4; ++jj) {
            float val = acc[i][jj] + bias[jc + jj];
            if (is_std) val = softplus_f(val);
            vp[jj] = val;
        }
        *(float4*)&out[off + (size_t)tt * HDIM + jc] = v;
    }
}

// ---------------------------------------------------------------------------
extern "C" void kernel_launch(void* const* d_in, const int* in_sizes, int n_in,
                              void* d_out, int out_size, void* d_ws, size_t ws_size,
                              hipStream_t stream) {
    (void)in_sizes; (void)n_in; (void)out_size; (void)ws_size;
    const float* actions = (const float*)d_in[0];
    const float* state   = (const float*)d_in[1];
    const float* W_ih    = (const float*)d_in[2];
    const float* W_hh    = (const float*)d_in[3];
    const float* b_ih    = (const float*)d_in[4];
    const float* b_hh    = (const float*)d_in[5];
    const float* fc1_w   = (const float*)d_in[6];
    const float* fc1_b   = (const float*)d_in[7];
    const float* fc2_w   = (const float*)d_in[8];
    const float* fc2_b   = (const float*)d_in[9];
    const float* mean_w  = (const float*)d_in[10];
    const float* mean_b  = (const float*)d_in[11];
    const float* std_w   = (const float*)d_in[12];
    const float* std_b   = (const float*)d_in[13];
    float* out = (float*)d_out;

    float* s_all = (float*)d_ws;                       // [T, H]
    float* s0    = s_all + (size_t)T_STEPS * HDIM;     // [H]
    float* s1    = s0 + HDIM;                          // [H]
    unsigned* flags = (unsigned*)(s1 + HDIM);          // [256] per-block tickets
    unsigned* gen   = flags + 256 + 32;                // own cacheline

    hipMemsetAsync(flags, 0, (256 + 64) * sizeof(unsigned), stream);

    void* args[] = { &actions, &state, &W_ih, &W_hh, &b_ih, &b_hh,
                     &fc1_w, &fc1_b, &fc2_w, &fc2_b,
                     &s_all, &s0, &s1, &flags, &gen };
    hipLaunchCooperativeKernel((const void*)gru_seq_kernel,
                               dim3(NBLK), dim3(NTHR), args, 0, stream);

    dim3 grid(4096 / 64, T_STEPS / 64);
    head_gemm_kernel<<<grid, 256, 0, stream>>>(s_all, mean_w, mean_b, std_w, std_b, out);
}

// Round 3
// 10862.019 us; speedup vs baseline: 6.0396x; 1.1401x over previous
//
#include <hip/hip_runtime.h>
#include <hip/hip_bf16.h>
#include <math.h>

#define T_STEPS 1024
#define HDIM    2048
#define ADIM    64
#define NBLK    256
#define NTHR    512
#define WPB     (NTHR / 64)   // 8 waves/block -> 2048 waves = one per output row

__device__ __forceinline__ float elu_f(float x)      { return x > 0.f ? x : expm1f(x); }
__device__ __forceinline__ float sigmoid_f(float x)  { return 1.f / (1.f + expf(-x)); }
__device__ __forceinline__ float softplus_f(float x) { return x > 0.f ? x + log1pf(expf(-x)) : log1pf(expf(x)); }

// Device-coherent relaxed 8B atomics. The tag lives in the high 32 bits and
// the float payload in the low 32 — one store publishes data+readiness
// atomically, so no fences / vmcnt drains / separate flags are needed.
__device__ __forceinline__ unsigned long long cload64(const unsigned long long* p) {
    return __hip_atomic_load(p, __ATOMIC_RELAXED, __HIP_MEMORY_SCOPE_AGENT);
}
__device__ __forceinline__ void cstore64(unsigned long long* p, unsigned long long v) {
    __hip_atomic_store(p, v, __ATOMIC_RELAXED, __HIP_MEMORY_SCOPE_AGENT);
}
__device__ __forceinline__ unsigned long long pack_tag(unsigned tag, float v) {
    return ((unsigned long long)tag << 32) | (unsigned long long)__float_as_uint(v);
}

// Spin until all 2048 tagged slots for `tag` are visible; stash payloads into
// LDS. Each thread owns 4 slots. Ends with __syncthreads (LDS fully staged).
__device__ __forceinline__ void consume_vec(const unsigned long long* __restrict__ tg,
                                            unsigned tag, float* __restrict__ lsv) {
    const int i = threadIdx.x;
    unsigned pend = 0xFu;
    while (pend) {
        #pragma unroll
        for (int q = 0; q < 4; ++q) {
            if (pend & (1u << q)) {
                const unsigned long long x = cload64(tg + i + q * NTHR);
                if ((unsigned)(x >> 32) == tag) {
                    lsv[i + q * NTHR] = __uint_as_float((unsigned)x);
                    pend &= ~(1u << q);
                }
            }
        }
    }
    __syncthreads();
}

// Pin a loaded float4 into VGPRs: the asm makes the value opaque so the
// register allocator cannot rematerialize the load inside the t-loop.
#define KEEP4(v) asm volatile("" : "+v"(v.x), "+v"(v.y), "+v"(v.z), "+v"(v.w))

// ---------------------------------------------------------------------------
// Persistent sequential kernel. Wave j holds its 5 weight rows (3x W_hh, fc1,
// fc2 = 160 VGPRs) register-resident. Per stage: poll tagged u64s -> LDS,
// dot vs register weights, wave-reduce, lane0 publishes one tagged u64.
// ---------------------------------------------------------------------------
__global__ void __launch_bounds__(NTHR, 2) gru_seq_kernel(
    const float* __restrict__ actions, const float* __restrict__ state,
    const float* __restrict__ W_ih, const float* __restrict__ W_hh,
    const float* __restrict__ b_ih, const float* __restrict__ b_hh,
    const float* __restrict__ fc1_w, const float* __restrict__ fc1_b,
    const float* __restrict__ fc2_w, const float* __restrict__ fc2_b,
    float* __restrict__ s_all,
    unsigned long long* __restrict__ tg0,
    unsigned long long* __restrict__ tg1,
    unsigned long long* __restrict__ tg2)
{
    __shared__ float lsv[HDIM];
    const int lane = threadIdx.x & 63;
    const int wave = threadIdx.x >> 6;
    const int j    = blockIdx.x * WPB + wave;   // 0..2047

    // --- prologue: weights -> registers ---
    float4 wr[8], wz[8], wn[8], f1[8], f2[8];
    {
        const float4* p0 = (const float4*)(W_hh + (size_t)j * HDIM);
        const float4* p1 = (const float4*)(W_hh + (size_t)(HDIM + j) * HDIM);
        const float4* p2 = (const float4*)(W_hh + (size_t)(2 * HDIM + j) * HDIM);
        const float4* p3 = (const float4*)(fc1_w + (size_t)j * HDIM);
        const float4* p4 = (const float4*)(fc2_w + (size_t)j * HDIM);
        #pragma unroll
        for (int i = 0; i < 8; ++i) {
            wr[i] = p0[i * 64 + lane]; KEEP4(wr[i]);
            wz[i] = p1[i * 64 + lane]; KEEP4(wz[i]);
            wn[i] = p2[i * 64 + lane]; KEEP4(wn[i]);
            f1[i] = p3[i * 64 + lane]; KEEP4(f1[i]);
            f2[i] = p4[i * 64 + lane]; KEEP4(f2[i]);
        }
    }
    const float wih_r = W_ih[(size_t)j * ADIM + lane];
    const float wih_z = W_ih[(size_t)(HDIM + j) * ADIM + lane];
    const float wih_n = W_ih[(size_t)(2 * HDIM + j) * ADIM + lane];
    const float bias_r = b_ih[j] + b_hh[j];
    const float bias_z = b_ih[HDIM + j] + b_hh[HDIM + j];
    const float bihn   = b_ih[2 * HDIM + j];
    const float bhhn   = b_hh[2 * HDIM + j];
    const float fb1    = fc1_b[j];
    const float fb2    = fc2_b[j];

    const float4* ls4 = (const float4*)lsv;

    for (int t = 0; t < T_STEPS; ++t) {
        const unsigned base = 3u * (unsigned)t;

        // ================= stage 1: GRU cell =================
        const float av = actions[t * ADIM + lane];   // independent; overlaps the spin
        if (t == 0) {
            #pragma unroll
            for (int q = 0; q < 4; ++q)
                lsv[threadIdx.x + q * NTHR] = state[threadIdx.x + q * NTHR];
            __syncthreads();
        } else {
            consume_vec(tg2, base, lsv);             // stage-3 output of t-1 (tag 3t)
        }
        {
            float dr = 0.f, dz = 0.f, dnH = 0.f;
            #pragma unroll
            for (int i = 0; i < 8; ++i) {
                const float4 s4 = ls4[i * 64 + lane];
                dr  += s4.x * wr[i].x + s4.y * wr[i].y + s4.z * wr[i].z + s4.w * wr[i].w;
                dz  += s4.x * wz[i].x + s4.y * wz[i].y + s4.z * wz[i].z + s4.w * wz[i].w;
                dnH += s4.x * wn[i].x + s4.y * wn[i].y + s4.z * wn[i].z + s4.w * wn[i].w;
            }
            float dnA = av * wih_n;
            dr += av * wih_r;
            dz += av * wih_z;
            #pragma unroll
            for (int m = 32; m > 0; m >>= 1) {
                dr  += __shfl_xor(dr, m, 64);
                dz  += __shfl_xor(dz, m, 64);
                dnH += __shfl_xor(dnH, m, 64);
                dnA += __shfl_xor(dnA, m, 64);
            }
            if (lane == 0) {
                const float r  = sigmoid_f(dr + bias_r);
                const float z  = sigmoid_f(dz + bias_z);
                const float n  = tanhf(dnA + bihn + r * (dnH + bhhn));
                const float hp = lsv[j];
                const float hn = (1.f - z) * n + z * hp;
                cstore64(&tg0[j], pack_tag(base + 1u, elu_f(hn)));
            }
        }
        __syncthreads();   // protect lsv before next consumer overwrites it

        // ================= stage 2: fc1 =================
        consume_vec(tg0, base + 1u, lsv);
        {
            float d1 = 0.f;
            #pragma unroll
            for (int i = 0; i < 8; ++i) {
                const float4 s4 = ls4[i * 64 + lane];
                d1 += s4.x * f1[i].x + s4.y * f1[i].y + s4.z * f1[i].z + s4.w * f1[i].w;
            }
            #pragma unroll
            for (int m = 32; m > 0; m >>= 1) d1 += __shfl_xor(d1, m, 64);
            if (lane == 0) cstore64(&tg1[j], pack_tag(base + 2u, elu_f(d1 + fb1)));
        }
        __syncthreads();

        // ================= stage 3: fc2 -> s_t =================
        consume_vec(tg1, base + 2u, lsv);
        {
            float d2 = 0.f;
            #pragma unroll
            for (int i = 0; i < 8; ++i) {
                const float4 s4 = ls4[i * 64 + lane];
                d2 += s4.x * f2[i].x + s4.y * f2[i].y + s4.z * f2[i].z + s4.w * f2[i].w;
            }
            #pragma unroll
            for (int m = 32; m > 0; m >>= 1) d2 += __shfl_xor(d2, m, 64);
            if (lane == 0) {
                const float v = elu_f(d2 + fb2);
                cstore64(&tg2[j], pack_tag(base + 3u, v));
                s_all[(size_t)t * HDIM + j] = v;   // plain store; head GEMM reads after kernel end
            }
        }
        __syncthreads();
    }
}

// ---------------------------------------------------------------------------
// Head GEMM: C[t, n], n<2048 -> mean, else softplus(std).
// ---------------------------------------------------------------------------
__global__ void __launch_bounds__(256) head_gemm_kernel(
    const float* __restrict__ s_all,
    const float* __restrict__ mean_w, const float* __restrict__ mean_b,
    const float* __restrict__ std_w,  const float* __restrict__ std_b,
    float* __restrict__ out)
{
    __shared__ float As[32 * 64];
    __shared__ float Bs[32 * 64];

    const int n0 = blockIdx.x * 64;
    const int t0 = blockIdx.y * 64;
    const bool is_std = (n0 >= HDIM);
    const float* W    = is_std ? std_w : mean_w;
    const float* bias = is_std ? std_b : mean_b;
    const int j0 = is_std ? (n0 - HDIM) : n0;

    const int tid = threadIdx.x;
    const int tx = tid & 15;
    const int ty = tid >> 4;

    float acc[4][4] = {};

    for (int k0 = 0; k0 < HDIM; k0 += 32) {
        __syncthreads();
        #pragma unroll
        for (int p = 0; p < 2; ++p) {
            const int id = tid + p * 256;
            const int m  = id >> 3;
            const int kk = id & 7;
            const float4 a = *(const float4*)&s_all[(size_t)(t0 + m) * HDIM + k0 + kk * 4];
            As[(kk * 4 + 0) * 64 + m] = a.x;
            As[(kk * 4 + 1) * 64 + m] = a.y;
            As[(kk * 4 + 2) * 64 + m] = a.z;
            As[(kk * 4 + 3) * 64 + m] = a.w;
            const float4 b = *(const float4*)&W[(size_t)(j0 + m) * HDIM + k0 + kk * 4];
            Bs[(kk * 4 + 0) * 64 + m] = b.x;
            Bs[(kk * 4 + 1) * 64 + m] = b.y;
            Bs[(kk * 4 + 2) * 64 + m] = b.z;
            Bs[(kk * 4 + 3) * 64 + m] = b.w;
        }
        __syncthreads();

        #pragma unroll
        for (int k = 0; k < 32; ++k) {
            const float4 a = *(const float4*)&As[k * 64 + ty * 4];
            const float4 b = *(const float4*)&Bs[k * 64 + tx * 4];
            const float am[4] = {a.x, a.y, a.z, a.w};
            const float bn[4] = {b.x, b.y, b.z, b.w};
            #pragma unroll
            for (int i = 0; i < 4; ++i)
                #pragma unroll
                for (int jj = 0; jj < 4; ++jj)
                    acc[i][jj] += am[i] * bn[jj];
        }
    }

    const size_t off = is_std ? (size_t)T_STEPS * HDIM : 0;
    #pragma unroll
    for (int i = 0; i < 4; ++i) {
        const int tt = t0 + ty * 4 + i;
        const int jc = j0 + tx * 4;
        float4 v;
        float* vp = (float*)&v;
        #pragma unroll
        for (int jj = 0; jj < 4; ++jj) {
            float val = acc[i][jj] + bias[jc + jj];
            if (is_std) val = softplus_f(val);
            vp[jj] = val;
        }
        *(float4*)&out[off + (size_t)tt * HDIM + jc] = v;
    }
}

// ---------------------------------------------------------------------------
extern "C" void kernel_launch(void* const* d_in, const int* in_sizes, int n_in,
                              void* d_out, int out_size, void* d_ws, size_t ws_size,
                              hipStream_t stream) {
    (void)in_sizes; (void)n_in; (void)out_size; (void)ws_size;
    const float* actions = (const float*)d_in[0];
    const float* state   = (const float*)d_in[1];
    const float* W_ih    = (const float*)d_in[2];
    const float* W_hh    = (const float*)d_in[3];
    const float* b_ih    = (const float*)d_in[4];
    const float* b_hh    = (const float*)d_in[5];
    const float* fc1_w   = (const float*)d_in[6];
    const float* fc1_b   = (const float*)d_in[7];
    const float* fc2_w   = (const float*)d_in[8];
    const float* fc2_b   = (const float*)d_in[9];
    const float* mean_w  = (const float*)d_in[10];
    const float* mean_b  = (const float*)d_in[11];
    const float* std_w   = (const float*)d_in[12];
    const float* std_b   = (const float*)d_in[13];
    float* out = (float*)d_out;

    float* s_all = (float*)d_ws;                              // [T, H] fp32
    unsigned long long* tg0 = (unsigned long long*)(s_all + (size_t)T_STEPS * HDIM);
    unsigned long long* tg1 = tg0 + HDIM;
    unsigned long long* tg2 = tg1 + HDIM;
    // no memset needed: 0xAA poison never matches a ticket (1..3072)

    void* args[] = { &actions, &state, &W_ih, &W_hh, &b_ih, &b_hh,
                     &fc1_w, &fc1_b, &fc2_w, &fc2_b,
                     &s_all, &tg0, &tg1, &tg2 };
    hipLaunchCooperativeKernel((const void*)gru_seq_kernel,
                               dim3(NBLK), dim3(NTHR), args, 0, stream);

    dim3 grid(4096 / 64, T_STEPS / 64);
    head_gemm_kernel<<<grid, 256, 0, stream>>>(s_all, mean_w, mean_b, std_w, std_b, out);
}